// Round 2
// baseline (1327.578 us; speedup 1.0000x reference)
//
#include <hip/hip_runtime.h>
#include <hip/hip_bf16.h>
#include <hip/hip_fp16.h>
#include <cstdint>
#include <cstddef>

#define AS1 __attribute__((address_space(1)))
#define AS3 __attribute__((address_space(3)))

constexpr int HIDC   = 4096;
constexpr int INTERC = 11008;
constexpr int NTOKC  = 4096;          // B*S
constexpr int NWGU   = 2 * INTERC;    // 22016 gate_up weight cols

using f32x4 = __attribute__((ext_vector_type(4))) float;
using f16x8 = __attribute__((ext_vector_type(8))) _Float16;

// ---------------- prologue kernels ----------------

// x f32 -> f16
__global__ void cvt_x_kernel(const float4* __restrict__ x, ushort4* __restrict__ xh, int n4) {
  int stride = gridDim.x * blockDim.x;
  for (int i = blockIdx.x * blockDim.x + threadIdx.x; i < n4; i += stride) {
    float4 v = x[i];
    ushort4 o;
    o.x = __builtin_bit_cast(unsigned short, __float2half(v.x));
    o.y = __builtin_bit_cast(unsigned short, __float2half(v.y));
    o.z = __builtin_bit_cast(unsigned short, __float2half(v.z));
    o.w = __builtin_bit_cast(unsigned short, __float2half(v.w));
    xh[i] = o;
  }
}

// repack qweight [K][N/8] (nibbles along N) -> qt [N][K/8] nibbles along K in
// PERMUTED order: k=j lands at nibble pos (j&1) ? 4+(j>>1) : (j>>1), so that
// (q >> 4i) & 0x000F000F extracts the k-pair (2i, 2i+1).
__global__ void repack_kernel(const uint32_t* __restrict__ qw, uint32_t* __restrict__ qt,
                              int kints, int Wn) {
  long total  = (long)Wn * kints;
  long stride = (long)gridDim.x * blockDim.x;
  for (long idx = blockIdx.x * (long)blockDim.x + threadIdx.x; idx < total; idx += stride) {
    int col = (int)(idx / kints);
    int kk  = (int)(idx - (long)col * kints);
    uint32_t ow[8] = {0, 0, 0, 0, 0, 0, 0, 0};
#pragma unroll
    for (int j = 0; j < 8; ++j) {
      uint32_t v = qw[(size_t)(kk * 8 + j) * Wn + col];
      const int pos = (j & 1) ? (4 + (j >> 1)) : (j >> 1);
#pragma unroll
      for (int jn = 0; jn < 8; ++jn)
        ow[jn] |= ((v >> (4 * jn)) & 0xFu) << (4 * pos);
    }
#pragma unroll
    for (int jn = 0; jn < 8; ++jn)
      qt[(size_t)(col * 8 + jn) * kints + kk] = ow[jn];
  }
}

// tab[g][n] = ( half2(s,s), half2(-z*s,-z*s) ) packed as uint2
__global__ void mktab_kernel(const uint32_t* __restrict__ qz, const float* __restrict__ sc,
                             uint2* __restrict__ tab, int total, int Nw) {
  int stride = gridDim.x * blockDim.x;
  for (int idx = blockIdx.x * blockDim.x + threadIdx.x; idx < total; idx += stride) {
    int g = idx / Nw, n = idx - g * Nw;
    uint32_t z = (qz[(size_t)g * (Nw >> 3) + (n >> 3)] >> ((n & 7) * 4)) & 0xFu;
    float s = sc[idx];
    uint32_t us = (uint32_t)__builtin_bit_cast(unsigned short, __float2half(s));
    uint32_t uc = (uint32_t)__builtin_bit_cast(unsigned short, __float2half(-s * (float)z));
    tab[idx] = make_uint2(us | (us << 16), uc | (uc << 16));
  }
}

// ---------------- fused dequant GEMM, 256x256 tile, depth-1 pipelined ----------------
// 512 threads = 8 waves (2 Mrows x 4 Ncols), per-wave output 128x64, BK=64.
// LDS: 2 buffers x (A 32KB + B 32KB) = 128KB. XOR swizzle byte^=(row&7)<<4.
// Single __syncthreads per K-tile: all writes go to buf^1 while reads come from buf.
template <int DUAL, int NT, int KINTS, int NWTOT, int NXT, int K>
__global__ __launch_bounds__(512, 2) void qgemm_kernel(
    const __half* __restrict__ A, const uint32_t* __restrict__ QT,
    const uint2* __restrict__ TAB, __half* __restrict__ Hout,
    float* __restrict__ Fout) {
  __shared__ __align__(16) char lds[131072];

  const int tid  = threadIdx.x;
  const int lane = tid & 63;
  const int w    = tid >> 6;
  const int wr   = w >> 2, wc = w & 3;
  const int fr   = lane & 15;
  const int fq   = lane >> 4;

  // bijective XCD chunking: each XCD gets a contiguous gid range; within a
  // chunk, N varies fastest so the A M-panel stays resident in that XCD's L2.
  const int nwg8 = (int)gridDim.x >> 3;
  const int g2   = (blockIdx.x & 7) * nwg8 + ((int)blockIdx.x >> 3);
  const int mt   = g2 / NXT;
  const int nt   = g2 - mt * NXT;
  const int row0 = mt * 256;

  // A staging: linear LDS dest (wave-uniform base + lane*16), pre-swizzled global src.
  int a_src[4];
#pragma unroll
  for (int i = 0; i < 4; ++i) {
    int o = i * 8192 + tid * 16;
    int r = o >> 7;
    int b = (o & 127) ^ ((r & 7) << 4);
    a_src[i] = (row0 + r) * K + (b >> 1);
  }

  // B staging: thread owns tile-col tc, k-half kh (32 nibbles = 4 q-words).
  const int tc = tid >> 1, kh = tid & 1;
  int wcol;
  if (DUAL) {
    // interleave gate/up at 16-col granularity so silu pairs are within-wave
    const int p = tc >> 5, mat = (tc >> 4) & 1, c16 = tc & 15;
    wcol = nt * 128 + p * 16 + c16 + mat * INTERC;
  } else {
    wcol = nt * 256 + tc;
  }
  const uint32_t* qbase = QT + (size_t)wcol * KINTS + kh * 4;
  const int boff = 32768 + tc * 128;
  const int bswz = (tc & 7) << 4;

  f32x4 acc[8][4] = {};

  auto stageA = [&](int kt, int buf) {
#pragma unroll
    for (int i = 0; i < 4; ++i)
      __builtin_amdgcn_global_load_lds((const AS1 uint32_t*)(A + a_src[i] + kt * 64),
                                       (AS3 uint32_t*)(lds + buf * 65536 + i * 8192 + w * 1024),
                                       16, 0, 0);
  };

  auto dequantB = [&](uint4 q, uint2 tz, int buf) {
    const __half2 s2 = __builtin_bit_cast(__half2, tz.x);
    const __half2 c2 = __builtin_bit_cast(__half2, tz.y);
    const __half2 k1024 = __builtin_bit_cast(__half2, 0x64006400u);
    char* bd = lds + buf * 65536 + boff;
    uint32_t qq[4] = {q.x, q.y, q.z, q.w};
#pragma unroll
    for (int ii = 0; ii < 4; ++ii) {
      uint32_t r[4];
#pragma unroll
      for (int i = 0; i < 4; ++i) {
        uint32_t pr = ((qq[ii] >> (4 * i)) & 0x000F000Fu) | 0x64006400u;
        __half2 t  = __hsub2(__builtin_bit_cast(__half2, pr), k1024);  // exact n pair
        __half2 wv = __hfma2(t, s2, c2);                               // n*s - z*s
        r[i] = __builtin_bit_cast(uint32_t, wv);
      }
      *(uint4*)(bd + ((kh * 64 + ii * 16) ^ bswz)) = make_uint4(r[0], r[1], r[2], r[3]);
    }
  };

  auto compute = [&](int buf) {
    const char* base = lds + buf * 65536;
#pragma unroll
    for (int kk = 0; kk < 2; ++kk) {
      const int bb = (((kk << 2) | fq) ^ (fr & 7)) << 4;
      f16x8 av[8], bv[4];
#pragma unroll
      for (int mi = 0; mi < 8; ++mi)
        av[mi] = *(const f16x8*)(base + (wr * 128 + mi * 16 + fr) * 128 + bb);
#pragma unroll
      for (int ni = 0; ni < 4; ++ni)
        bv[ni] = *(const f16x8*)(base + 32768 + (wc * 64 + ni * 16 + fr) * 128 + bb);
      __builtin_amdgcn_s_setprio(1);
#pragma unroll
      for (int mi = 0; mi < 8; ++mi)
#pragma unroll
        for (int ni = 0; ni < 4; ++ni)
          acc[mi][ni] = __builtin_amdgcn_mfma_f32_16x16x32_f16(av[mi], bv[ni], acc[mi][ni], 0, 0, 0);
      __builtin_amdgcn_s_setprio(0);
    }
  };

  // prologue: tile 0 into buf0
  uint4 q  = *(const uint4*)qbase;
  uint2 tz = TAB[(size_t)wcol];     // g=0
  stageA(0, 0);
  dequantB(q, tz, 0);
  __syncthreads();
  q  = *(const uint4*)(qbase + 8);  // tile 1 (NT>=2 always)
  tz = TAB[(size_t)(1 >> 1) * NWTOT + wcol];

  int cur = 0;
#pragma unroll 1
  for (int kt = 0; kt < NT; ++kt) {
    if (kt + 1 < NT) {
      stageA(kt + 1, cur ^ 1);
      dequantB(q, tz, cur ^ 1);
    }
    if (kt + 2 < NT) {
      q  = *(const uint4*)(qbase + (kt + 2) * 8);
      tz = TAB[(size_t)((kt + 2) >> 1) * NWTOT + wcol];
    }
    compute(cur);
    __syncthreads();
    cur ^= 1;
  }

  // epilogue — C/D map: col = lane&15 (fr), row = fq*4 + reg
  if (DUAL) {
#pragma unroll
    for (int mi = 0; mi < 8; ++mi) {
      const int rr = row0 + wr * 128 + mi * 16 + fq * 4;
#pragma unroll
      for (int pp = 0; pp < 2; ++pp) {
        const int hcol = nt * 128 + (wc * 2 + pp) * 16 + fr;
#pragma unroll
        for (int r = 0; r < 4; ++r) {
          float gv = acc[mi][2 * pp][r];
          float uv = acc[mi][2 * pp + 1][r];
          float hv = gv / (1.0f + __expf(-gv)) * uv;
          Hout[(size_t)(rr + r) * INTERC + hcol] = __float2half(hv);
        }
      }
    }
  } else {
#pragma unroll
    for (int mi = 0; mi < 8; ++mi) {
      const int rr = row0 + wr * 128 + mi * 16 + fq * 4;
#pragma unroll
      for (int ni = 0; ni < 4; ++ni) {
        const int cc = nt * 256 + wc * 64 + ni * 16 + fr;
#pragma unroll
        for (int r = 0; r < 4; ++r)
          Fout[(size_t)(rr + r) * HIDC + cc] = acc[mi][ni][r];
      }
    }
  }
}

// ---------------- launch ----------------
extern "C" void kernel_launch(void* const* d_in, const int* in_sizes, int n_in,
                              void* d_out, int out_size, void* d_ws, size_t ws_size,
                              hipStream_t stream) {
  const float*    x     = (const float*)d_in[0];
  const uint32_t* qw_gu = (const uint32_t*)d_in[1];
  const uint32_t* qz_gu = (const uint32_t*)d_in[2];
  const float*    sc_gu = (const float*)d_in[3];
  const uint32_t* qw_dn = (const uint32_t*)d_in[4];
  const uint32_t* qz_dn = (const uint32_t*)d_in[5];
  const float*    sc_dn = (const float*)d_in[6];
  float* out = (float*)d_out;

  // workspace layout (bytes), ~199.8 MB
  char* ws = (char*)d_ws;
  __half*   xh   = (__half*)(ws + 0);                 // 33,554,432
  uint32_t* qtgu = (uint32_t*)(ws + 33554432);        // 45,088,768
  uint32_t* qtdn = (uint32_t*)(ws + 78643200);        // 22,544,384
  uint2*    tgu  = (uint2*)(ws + 101187584);          //  5,636,096
  uint2*    tdn  = (uint2*)(ws + 106823680);          //  2,818,048
  __half*   hbuf = (__half*)(ws + 109641728);         // 90,177,536

  cvt_x_kernel<<<2048, 256, 0, stream>>>((const float4*)x, (ushort4*)xh, NTOKC * HIDC / 4);
  repack_kernel<<<2048, 256, 0, stream>>>(qw_gu, qtgu, HIDC / 8, NWGU / 8);
  repack_kernel<<<2048, 256, 0, stream>>>(qw_dn, qtdn, INTERC / 8, HIDC / 8);
  mktab_kernel<<<1024, 256, 0, stream>>>(qz_gu, sc_gu, tgu, (HIDC / 128) * NWGU, NWGU);
  mktab_kernel<<<1024, 256, 0, stream>>>(qz_dn, sc_dn, tdn, (INTERC / 128) * HIDC, HIDC);

  // GEMM1: x[4096x4096] @ W_gu -> silu*mul -> h f16 [4096x11008]; 86x16=1376 blocks
  qgemm_kernel<1, 64, 512, NWGU, 86, HIDC>
      <<<1376, 512, 0, stream>>>(xh, qtgu, tgu, hbuf, nullptr);
  // GEMM2: h @ W_dn -> out f32 [4096x4096]; 16x16=256 blocks
  qgemm_kernel<0, 172, 1376, HIDC, 16, INTERC>
      <<<256, 512, 0, stream>>>(hbuf, qtdn, tdn, nullptr, out);
}